// Round 2
// baseline (2041.296 us; speedup 1.0000x reference)
//
#include <hip/hip_runtime.h>
#include <hip/hip_bf16.h>
#include <cstdint>
#include <cstddef>

#define NUM_G   7
#define E_EDGES 100000
#define N_NODES 20000
#define U_NODES 10000
#define B_SZ    1024
#define HCC     256     // H*C
#define FIN     128
#define NC      768     // combined cols: [xh | a_src | a_dst]
#define ITEMS   50000

// ---------------- Wcomb precompute: [W | W@BD(att_src) | W@BD(att_dst)] ----------------
// a_src[n,h,d] = sum_c xh[n,h,c] att_src[h,c,d]; xh = x@W  =>  a_src = x @ Wse
// Wse[i, h*64+d] = sum_c W[i, h*64+c] * att_src[h,c,d]
__global__ void wcomb_kernel(const float* __restrict__ convs_W,
                             const float* __restrict__ convs_as,
                             const float* __restrict__ convs_ad,
                             const float* __restrict__ uW,
                             const float* __restrict__ u_as,
                             const float* __restrict__ u_ad,
                             float* __restrict__ Wcomb) {
    int gid = blockIdx.x * 256 + threadIdx.x;          // 8 * 128 * 768 threads total
    int conv = gid / (FIN * NC);
    int rem  = gid % (FIN * NC);
    int i = rem / NC, j = rem % NC;
    const float* W = (conv < NUM_G) ? convs_W + (size_t)conv * FIN * HCC : uW;
    float v;
    if (j < HCC) {
        v = W[i * HCC + j];
    } else {
        int which = (j - HCC) / HCC;                   // 0 = src, 1 = dst
        int jj = (j - HCC) % HCC;
        int h = jj / 64, d = jj % 64;
        const float* att;
        if (which == 0) att = (conv < NUM_G) ? convs_as + (size_t)conv * 4 * 64 * 64 : u_as;
        else            att = (conv < NUM_G) ? convs_ad + (size_t)conv * 4 * 64 * 64 : u_ad;
        att += h * 64 * 64;
        const float* wrow = W + i * HCC + h * 64;
        float s = 0.f;
        #pragma unroll 4
        for (int c = 0; c < 64; ++c) s += wrow[c] * att[c * 64 + d];
        v = s;
    }
    Wcomb[gid] = v;
}

// ---------------- mask build ----------------
__global__ void mask_zero_kernel(int* __restrict__ m, int n) {
    int i = blockIdx.x * 256 + threadIdx.x;
    if (i < n) m[i] = 0;
}

__global__ void mask_set_kernel(const int* __restrict__ g_center,
                                const int* __restrict__ anchors,
                                int* __restrict__ masks) {
    int t = blockIdx.x * 256 + threadIdx.x;            // 8 * 1024 threads
    int conv = t / B_SZ, b = t % B_SZ;
    if (conv < NUM_G) masks[conv * N_NODES + g_center[conv * B_SZ + b]] = 1;
    else              masks[NUM_G * N_NODES + anchors[b]] = 1;
}

// ---------------- per-conv init: zero only the rows that receive atomics ----------------
__global__ void zero_rows_kernel(const int* __restrict__ center,
                                 float* __restrict__ denom, float* __restrict__ outun) {
    int b = blockIdx.x; int c = threadIdx.x;           // grid B_SZ x 256
    int row = center[b];
    denom[(size_t)row * HCC + c] = 0.f;
    outun[(size_t)row * HCC + c] = 0.f;
}

// ---------------- edge pass: one wave per edge, skip non-center dst ----------------
__global__ void edge_kernel(const int* __restrict__ src, const int* __restrict__ dst,
                            const float* __restrict__ xa, const int* __restrict__ mask,
                            float* __restrict__ denom, float* __restrict__ outun, int E) {
    int w = threadIdx.x >> 6;
    int lane = threadIdx.x & 63;
    int e = blockIdx.x * 4 + w;
    if (e >= E) return;
    int d = dst[e];
    if (mask[d] == 0) return;                          // dst never read at centers -> skip
    int s = src[e];
    const float4* ps = (const float4*)(xa + (size_t)s * NC);
    const float4* pd = (const float4*)(xa + (size_t)d * NC);
    float4 xh = ps[lane];                              // xh[s, lane*4 ..]
    float4 as = ps[64 + lane];                         // a_src[s, ...] (+256 floats)
    float4 ad = pd[128 + lane];                        // a_dst[d, ...] (+512 floats)
    float* dden = denom + (size_t)d * HCC + lane * 4;
    float* dout = outun + (size_t)d * HCC + lane * 4;
    float ev[4] = {as.x + ad.x, as.y + ad.y, as.z + ad.z, as.w + ad.w};
    float xv[4] = {xh.x, xh.y, xh.z, xh.w};
    #pragma unroll
    for (int j = 0; j < 4; ++j) {
        float t = ev[j];
        t = (t >= 0.f) ? t : 0.2f * t;                 // leaky_relu, slope 0.2
        float p = expf(t);                             // emax shift cancels in the quotient
        atomicAdd(dden + j, p);
        atomicAdd(dout + j, p * xv[j]);
    }
}

// ---------------- finalize: gather at centers, normalize, + bias ----------------
__global__ void finalize_kernel(const int* __restrict__ center,
                                const float* __restrict__ denom,
                                const float* __restrict__ outun,
                                const float* __restrict__ bias,
                                float* __restrict__ dest, int ldc) {
    int b = blockIdx.x; int c = threadIdx.x;           // grid B_SZ x 256
    int row = center[b];
    float v = outun[(size_t)row * HCC + c] / (denom[(size_t)row * HCC + c] + 1e-16f) + bias[c];
    dest[(size_t)b * ldc + c] = v;
}

// ---------------- stp averaging into X1 = [ (s+t+f)/3 | (s_rw+t_rw+f_rw)/3 ] ----------------
__global__ void avg_kernel(const float* __restrict__ outs, float* __restrict__ X1) {
    int b = blockIdx.x, c = threadIdx.x;               // grid B_SZ x 256
    size_t off = (size_t)b * HCC + c;
    const size_t S = (size_t)B_SZ * HCC;
    float v1 = (outs[off] + outs[S + off] + outs[2 * S + off]) / 3.0f;
    float v2 = (outs[3 * S + off] + outs[4 * S + off] + outs[5 * S + off]) / 3.0f;
    X1[(size_t)b * 512 + c] = v1;
    X1[(size_t)b * 512 + 256 + c] = v2;
}

// ---------------- generic fp32 GEMM with optional row gather + bias ----------------
// C[M,N] = gatherA(M rows) @ B[K,N] (+bias). BM=128, BN=64, BK=32; 256 thr; 8x4 acc/thread.
template<int BM, int BN, int BK>
__launch_bounds__(256)
__global__ void gemm_kernel(const float* __restrict__ A, const int* __restrict__ idx, int lda,
                            const float* __restrict__ B, int ldb,
                            float* __restrict__ C, int ldc,
                            const float* __restrict__ bias,
                            int M, int N, int K) {
    __shared__ float As[BK][BM + 4];   // transposed A tile: As[k][m], pad keeps b128 align
    __shared__ float Bs[BK][BN + 4];
    int tid = threadIdx.x;
    int m0 = blockIdx.y * BM, n0 = blockIdx.x * BN;
    int tr = tid / 16, tc = tid % 16;  // rows tr*8..+7, cols tc*4..+3
    float acc[8][4];
    #pragma unroll
    for (int i = 0; i < 8; ++i)
        #pragma unroll
        for (int j = 0; j < 4; ++j) acc[i][j] = 0.f;

    for (int kb = 0; kb < K; kb += BK) {
        // stage A (BM x BK) -> transposed
        #pragma unroll
        for (int it = 0; it < (BM * BK) / (256 * 4); ++it) {
            int r = tid / 8 + it * 32;
            int kk = (tid % 8) * 4;
            int gr = m0 + r;
            float4 v = make_float4(0.f, 0.f, 0.f, 0.f);
            if (gr < M) {
                int ar = idx ? idx[gr] : gr;
                v = *(const float4*)&A[(size_t)ar * lda + kb + kk];
            }
            As[kk + 0][r] = v.x; As[kk + 1][r] = v.y;
            As[kk + 2][r] = v.z; As[kk + 3][r] = v.w;
        }
        // stage B (BK x BN)
        #pragma unroll
        for (int it = 0; it < (BK * BN) / (256 * 4); ++it) {
            int kk = tid / 16 + it * 16;
            int n = (tid % 16) * 4;
            int gn = n0 + n;
            const float* bp = &B[(size_t)(kb + kk) * ldb + gn];
            float4 v;
            if (gn + 3 < N) v = *(const float4*)bp;
            else {
                v.x = (gn + 0 < N) ? bp[0] : 0.f;
                v.y = (gn + 1 < N) ? bp[1] : 0.f;
                v.z = (gn + 2 < N) ? bp[2] : 0.f;
                v.w = (gn + 3 < N) ? bp[3] : 0.f;
            }
            *(float4*)&Bs[kk][n] = v;
        }
        __syncthreads();
        #pragma unroll
        for (int kk = 0; kk < BK; ++kk) {
            float4 a0 = *(const float4*)&As[kk][tr * 8];
            float4 a1 = *(const float4*)&As[kk][tr * 8 + 4];
            float4 b0 = *(const float4*)&Bs[kk][tc * 4];
            float a[8] = {a0.x, a0.y, a0.z, a0.w, a1.x, a1.y, a1.z, a1.w};
            float b[4] = {b0.x, b0.y, b0.z, b0.w};
            #pragma unroll
            for (int i = 0; i < 8; ++i)
                #pragma unroll
                for (int j = 0; j < 4; ++j)
                    acc[i][j] += a[i] * b[j];
        }
        __syncthreads();
    }
    #pragma unroll
    for (int i = 0; i < 8; ++i) {
        int gr = m0 + tr * 8 + i;
        if (gr >= M) continue;
        #pragma unroll
        for (int j = 0; j < 4; ++j) {
            int gc = n0 + tc * 4 + j;
            if (gc < N) {
                float v = acc[i][j];
                if (bias) v += bias[gc];
                C[(size_t)gr * ldc + gc] = v;
            }
        }
    }
}

extern "C" void kernel_launch(void* const* d_in, const int* in_sizes, int n_in,
                              void* d_out, int out_size, void* d_ws, size_t ws_size,
                              hipStream_t stream) {
    const int*   g_node_idx   = (const int*)d_in[0];
    const int*   g_edge_index = (const int*)d_in[1];
    const int*   g_center     = (const int*)d_in[2];
    const int*   u_eindex     = (const int*)d_in[3];
    const int*   anchors      = (const int*)d_in[4];
    const float* item_emb     = (const float*)d_in[5];
    const float* user_emb     = (const float*)d_in[6];
    const float* convs_W      = (const float*)d_in[7];
    const float* convs_as     = (const float*)d_in[8];
    const float* convs_ad     = (const float*)d_in[9];
    const float* convs_bias   = (const float*)d_in[10];
    const float* u_W          = (const float*)d_in[11];
    const float* u_as         = (const float*)d_in[12];
    const float* u_ad         = (const float*)d_in[13];
    const float* u_bias       = (const float*)d_in[14];
    const float* a_rw_W       = (const float*)d_in[15];
    const float* a_rw_b       = (const float*)d_in[16];
    const float* pp_stp_W     = (const float*)d_in[17];
    const float* pp_stp_b     = (const float*)d_in[18];
    const float* final_W      = (const float*)d_in[19];
    const float* final_b      = (const float*)d_in[20];

    // Big transients live in d_out (204.8 MB); all dead before the final GEMM
    // overwrites the whole buffer with logits. FR must survive that GEMM -> ws.
    float* ob    = (float*)d_out;
    float* xa    = ob;                   // 20000*768      [xh | a_src | a_dst]
    float* denom = ob + 15360000;        // 20000*256
    float* outun = ob + 20480000;        // 20000*256
    float* Wcomb = ob + 25600000;        // 8*128*768 = 786432
    float* outs  = ob + 26386432;        // 6*1024*256
    float* X1    = ob + 27959296;        // 1024*512
    float* X2    = ob + 28483584;        // 1024*512  [pp_x | stp]
    int*   masks = (int*)(ob + 29007872);// 7*20000 + 10000 ints  (ends < 29.16M floats)
    float* FR    = (float*)d_ws;         // 1024*512  [y | u_x]  (2 MB in workspace)

    dim3 blk(256);

    wcomb_kernel<<<3072, blk, 0, stream>>>(convs_W, convs_as, convs_ad, u_W, u_as, u_ad, Wcomb);
    mask_zero_kernel<<<(150000 + 255) / 256, blk, 0, stream>>>(masks, 150000);
    mask_set_kernel<<<32, blk, 0, stream>>>(g_center, anchors, masks);

    for (int g = 0; g < NUM_G; ++g) {
        gemm_kernel<128, 64, 32><<<dim3(12, 157), blk, 0, stream>>>(
            item_emb, g_node_idx + g * N_NODES, FIN,
            Wcomb + (size_t)g * FIN * NC, NC, xa, NC, nullptr, N_NODES, NC, FIN);
        zero_rows_kernel<<<B_SZ, blk, 0, stream>>>(g_center + g * B_SZ, denom, outun);
        edge_kernel<<<E_EDGES / 4, blk, 0, stream>>>(
            g_edge_index + (size_t)g * 2 * E_EDGES,
            g_edge_index + (size_t)g * 2 * E_EDGES + E_EDGES,
            xa, masks + g * N_NODES, denom, outun, E_EDGES);
        float* dest = (g < 6) ? outs + (size_t)g * B_SZ * HCC : X2;  // g==6 (pp) -> X2 first half
        int ldc = (g < 6) ? HCC : 512;
        finalize_kernel<<<B_SZ, blk, 0, stream>>>(
            g_center + g * B_SZ, denom, outun, convs_bias + g * HCC, dest, ldc);
    }

    // user graph conv (identity gather, 10000 nodes)
    gemm_kernel<128, 64, 32><<<dim3(12, 79), blk, 0, stream>>>(
        user_emb, nullptr, FIN,
        Wcomb + (size_t)NUM_G * FIN * NC, NC, xa, NC, nullptr, U_NODES, NC, FIN);
    zero_rows_kernel<<<B_SZ, blk, 0, stream>>>(anchors, denom, outun);
    edge_kernel<<<E_EDGES / 4, blk, 0, stream>>>(
        u_eindex, u_eindex + E_EDGES, xa, masks + NUM_G * N_NODES, denom, outun, E_EDGES);
    finalize_kernel<<<B_SZ, blk, 0, stream>>>(
        anchors, denom, outun, u_bias, FR + 256, 512);                // u_x -> FR second half

    avg_kernel<<<B_SZ, blk, 0, stream>>>(outs, X1);
    // stp = X1 @ a_rw_W + b  -> X2 second half
    gemm_kernel<128, 64, 32><<<dim3(4, 8), blk, 0, stream>>>(
        X1, nullptr, 512, a_rw_W, HCC, X2 + 256, 512, a_rw_b, B_SZ, HCC, 512);
    // y = X2 @ pp_stp_W + b  -> FR first half
    gemm_kernel<128, 64, 32><<<dim3(4, 8), blk, 0, stream>>>(
        X2, nullptr, 512, pp_stp_W, HCC, FR, 512, pp_stp_b, B_SZ, HCC, 512);
    // logits = FR @ final_W + final_b -> d_out (overwrites all scratch)
    gemm_kernel<128, 64, 32><<<dim3(782, 8), blk, 0, stream>>>(
        FR, nullptr, 512, final_W, ITEMS, ob, ITEMS, final_b, B_SZ, ITEMS, 512);
}

// Round 3
// 1305.893 us; speedup vs baseline: 1.5631x; 1.5631x over previous
//
#include <hip/hip_runtime.h>
#include <hip/hip_bf16.h>
#include <cstdint>
#include <cstddef>

#define NUM_G   7
#define E_EDGES 100000
#define N_NODES 20000
#define U_NODES 10000
#define B_SZ    1024
#define HCC     256     // H*C
#define FIN     128
#define NC      768     // combined cols: [xh | a_src | a_dst]
#define ITEMS   50000

typedef float f32x4 __attribute__((ext_vector_type(4)));
typedef short s16x8 __attribute__((ext_vector_type(8)));

__device__ inline short f2bf(float f) {              // RNE f32 -> bf16
    uint32_t x = __builtin_bit_cast(uint32_t, f);
    uint32_t r = (x + 0x7FFFu + ((x >> 16) & 1u)) >> 16;
    return (short)r;
}

// ---------------- Wcomb precompute -> bf16, B^T layout [conv][n=768][k=128] ----------
// Wse[k, h*64+d] = sum_c W[k, h*64+c] * att[h,c,d];  stored transposed for MFMA B-side.
__global__ void wcomb_kernel(const float* __restrict__ convs_W,
                             const float* __restrict__ convs_as,
                             const float* __restrict__ convs_ad,
                             const float* __restrict__ uW,
                             const float* __restrict__ u_as,
                             const float* __restrict__ u_ad,
                             short* __restrict__ Wcombb) {
    int gid = blockIdx.x * 256 + threadIdx.x;        // 8 * 768 * 128, i fastest
    int conv = gid / (NC * FIN);
    int rem  = gid % (NC * FIN);
    int j = rem / FIN, i = rem % FIN;                // j = output col (0..767), i = k (0..127)
    const float* W = (conv < NUM_G) ? convs_W + (size_t)conv * FIN * HCC : uW;
    float v;
    if (j < HCC) {
        v = W[i * HCC + j];
    } else {
        int which = (j - HCC) / HCC;                 // 0 = src, 1 = dst
        int jj = (j - HCC) % HCC;
        int h = jj / 64, d = jj % 64;
        const float* att;
        if (which == 0) att = (conv < NUM_G) ? convs_as + (size_t)conv * 4 * 64 * 64 : u_as;
        else            att = (conv < NUM_G) ? convs_ad + (size_t)conv * 4 * 64 * 64 : u_ad;
        att += h * 64 * 64;
        const float* wrow = W + i * HCC + h * 64;
        float s = 0.f;
        #pragma unroll 4
        for (int c = 0; c < 64; ++c) s += wrow[c] * att[c * 64 + d];
        v = s;
    }
    Wcombb[gid] = f2bf(v);
}

// ---------------- flat f32 -> bf16 convert (n4 = quads) ----------------
__global__ void conv_bf16_kernel(const float* __restrict__ in, short* __restrict__ out, int n4) {
    int i = blockIdx.x * 256 + threadIdx.x;
    if (i >= n4) return;
    float4 v = ((const float4*)in)[i];
    short4 o; o.x = f2bf(v.x); o.y = f2bf(v.y); o.z = f2bf(v.z); o.w = f2bf(v.w);
    *(short4*)&out[(size_t)i * 4] = o;
}

// ---------------- transpose+convert: f32 [K][N] -> bf16 [N][K] (K,N mult of 64) ------
__global__ void tconv_kernel(const float* __restrict__ in, short* __restrict__ out, int K, int N) {
    __shared__ float t[64][65];
    int n0 = blockIdx.x * 64, k0 = blockIdx.y * 64;
    int r = threadIdx.x >> 4, c4 = (threadIdx.x & 15) * 4;
    #pragma unroll
    for (int rr = 0; rr < 4; ++rr) {
        int k = r + rr * 16;
        *(float4*)&t[k][c4] = *(const float4*)&in[(size_t)(k0 + k) * N + n0 + c4];
    }
    __syncthreads();
    #pragma unroll
    for (int rr = 0; rr < 4; ++rr) {
        int n = r + rr * 16;
        short4 o;
        o.x = f2bf(t[c4 + 0][n]); o.y = f2bf(t[c4 + 1][n]);
        o.z = f2bf(t[c4 + 2][n]); o.w = f2bf(t[c4 + 3][n]);
        *(short4*)&out[(size_t)(n0 + n) * K + k0 + c4] = o;
    }
}

// ---------------- mask build ----------------
__global__ void mask_zero_kernel(int* __restrict__ m, int n) {
    int i = blockIdx.x * 256 + threadIdx.x;
    if (i < n) m[i] = 0;
}

__global__ void mask_set_kernel(const int* __restrict__ g_center,
                                const int* __restrict__ anchors,
                                int* __restrict__ masks) {
    int t = blockIdx.x * 256 + threadIdx.x;          // 8 * 1024 threads
    int conv = t / B_SZ, b = t % B_SZ;
    if (conv < NUM_G) masks[conv * N_NODES + g_center[conv * B_SZ + b]] = 1;
    else              masks[NUM_G * N_NODES + anchors[b]] = 1;
}

// ---------------- per-conv init: zero only the rows that receive atomics -------------
__global__ void zero_rows_kernel(const int* __restrict__ center,
                                 float* __restrict__ denom, float* __restrict__ outun) {
    int b = blockIdx.x; int c = threadIdx.x;         // grid B_SZ x 256
    int row = center[b];
    denom[(size_t)row * HCC + c] = 0.f;
    outun[(size_t)row * HCC + c] = 0.f;
}

// ---------------- edge pass: one wave per edge, skip non-center dst -------------------
__global__ void edge_kernel(const int* __restrict__ src, const int* __restrict__ dst,
                            const float* __restrict__ xa, const int* __restrict__ mask,
                            float* __restrict__ denom, float* __restrict__ outun, int E) {
    int w = threadIdx.x >> 6;
    int lane = threadIdx.x & 63;
    int e = blockIdx.x * 4 + w;
    if (e >= E) return;
    int d = dst[e];
    if (mask[d] == 0) return;                        // dst never read at centers -> skip
    int s = src[e];
    const float4* ps = (const float4*)(xa + (size_t)s * NC);
    const float4* pd = (const float4*)(xa + (size_t)d * NC);
    float4 xh = ps[lane];
    float4 as = ps[64 + lane];
    float4 ad = pd[128 + lane];
    float* dden = denom + (size_t)d * HCC + lane * 4;
    float* dout = outun + (size_t)d * HCC + lane * 4;
    float ev[4] = {as.x + ad.x, as.y + ad.y, as.z + ad.z, as.w + ad.w};
    float xv[4] = {xh.x, xh.y, xh.z, xh.w};
    #pragma unroll
    for (int j = 0; j < 4; ++j) {
        float t = ev[j];
        t = (t >= 0.f) ? t : 0.2f * t;               // leaky_relu, slope 0.2
        float p = expf(t);                           // emax shift cancels in the quotient
        atomicAdd(dden + j, p);
        atomicAdd(dout + j, p * xv[j]);
    }
}

// ---------------- finalize: gather at centers, normalize, + bias -> bf16 -------------
__global__ void finalize_kernel(const int* __restrict__ center,
                                const float* __restrict__ denom,
                                const float* __restrict__ outun,
                                const float* __restrict__ bias,
                                short* __restrict__ dest, int ldc) {
    int b = blockIdx.x; int c = threadIdx.x;         // grid B_SZ x 256
    int row = center[b];
    float v = outun[(size_t)row * HCC + c] / (denom[(size_t)row * HCC + c] + 1e-16f) + bias[c];
    dest[(size_t)b * ldc + c] = f2bf(v);
}

// ---------------- stp averaging (bf16 in/out) ----------------
__global__ void avg_kernel(const short* __restrict__ outs, short* __restrict__ X1) {
    int b = blockIdx.x, c = threadIdx.x;             // grid B_SZ x 256
    size_t off = (size_t)b * HCC + c;
    const size_t S = (size_t)B_SZ * HCC;
    auto ld = [](short s) { return __builtin_bit_cast(float, (uint32_t)(unsigned short)s << 16); };
    float v1 = (ld(outs[off]) + ld(outs[S + off]) + ld(outs[2 * S + off])) / 3.0f;
    float v2 = (ld(outs[3 * S + off]) + ld(outs[4 * S + off]) + ld(outs[5 * S + off])) / 3.0f;
    X1[(size_t)b * 512 + c] = f2bf(v1);
    X1[(size_t)b * 512 + 256 + c] = f2bf(v2);
}

// ---------------- bf16 MFMA GEMM ----------------
// C[M,N](f32 or bf16) = gatherA[M,K](bf16) @ B (+bias).
// B is either bf16 B^T [N][ldb] (BF32=false) or f32 [K][ldb] row-major (BF32=true,
// converted+transposed during LDS staging). BM=BN=128, BK=32, 256 thr = 4 waves (2x2),
// wave tile 64x64 = 4x4 frags of mfma_f32_16x16x32_bf16.
template<bool GATHER, bool OUT_BF16, bool BF32, bool SWZ>
__launch_bounds__(256)
__global__ void mgemm(const short* __restrict__ A, const int* __restrict__ idx, int lda,
                      const void* __restrict__ Bv, int ldb,
                      void* __restrict__ C, int ldc, const float* __restrict__ bias,
                      int M, int N, int K) {
    const int BKP = 40;                              // padded k-stride (bf16 elems)
    __shared__ __align__(16) short As[128 * BKP];
    __shared__ __align__(16) short Bs[128 * BKP];
    int tid = threadIdx.x;
    int lane = tid & 63, w = tid >> 6;
    int wr = w >> 1, wc = w & 1;
    int lr = lane & 15, kq = lane >> 4;
    int m0, n0;
    if (SWZ) {                                       // XCD-chunked: requires gridDim.x==8
        int b = blockIdx.x + (blockIdx.y << 3);
        int L = (b & 7) * gridDim.y + (b >> 3);      // XCD k owns contiguous col range
        m0 = (L & 7) * 128;
        n0 = (L >> 3) * 128;
    } else {
        m0 = blockIdx.y * 128; n0 = blockIdx.x * 128;
    }

    f32x4 acc[4][4];
    #pragma unroll
    for (int i = 0; i < 4; ++i)
        #pragma unroll
        for (int j = 0; j < 4; ++j)
            #pragma unroll
            for (int r = 0; r < 4; ++r) acc[i][j][r] = 0.f;

    // hoisted per-thread staging coords
    long arow[2]; int brow[2]; bool aok[2], bok[2];
    #pragma unroll
    for (int it = 0; it < 2; ++it) {
        int c = tid + it * 256;
        int r = c >> 2;
        int gr = m0 + r;
        aok[it] = gr < M;
        arow[it] = aok[it] ? (GATHER ? (long)idx[gr] : (long)gr) : 0;
        int gn = n0 + r;
        bok[it] = gn < N;
        brow[it] = gn;
    }

    for (int kb = 0; kb < K; kb += 32) {
        // ---- stage A (bf16 rows, contiguous k) ----
        #pragma unroll
        for (int it = 0; it < 2; ++it) {
            int c = tid + it * 256;
            int r = c >> 2, k8 = (c & 3) * 8;
            s16x8 v = {};
            if (aok[it]) v = *(const s16x8*)&A[arow[it] * lda + kb + k8];
            *(s16x8*)&As[r * BKP + k8] = v;
        }
        // ---- stage B ----
        if (!BF32) {
            const short* BT = (const short*)Bv;
            #pragma unroll
            for (int it = 0; it < 2; ++it) {
                int c = tid + it * 256;
                int r = c >> 2, k8 = (c & 3) * 8;
                s16x8 v = {};
                if (bok[it]) v = *(const s16x8*)&BT[(long)brow[it] * ldb + kb + k8];
                *(s16x8*)&Bs[r * BKP + k8] = v;
            }
        } else {
            const float* Bf = (const float*)Bv;
            #pragma unroll
            for (int it = 0; it < 4; ++it) {
                int c = tid + it * 256;              // 1024 float4-chunks of 32x128 tile
                int k = c >> 5, n4 = (c & 31) * 4;
                int gn = n0 + n4;
                float4 v = make_float4(0.f, 0.f, 0.f, 0.f);
                const float* bp = &Bf[(size_t)(kb + k) * ldb + gn];
                if (gn + 3 < N) v = *(const float4*)bp;
                else {
                    if (gn + 0 < N) v.x = bp[0];
                    if (gn + 1 < N) v.y = bp[1];
                    if (gn + 2 < N) v.z = bp[2];
                    if (gn + 3 < N) v.w = bp[3];
                }
                short b4[4] = {f2bf(v.x), f2bf(v.y), f2bf(v.z), f2bf(v.w)};
                #pragma unroll
                for (int jj = 0; jj < 4; ++jj) {     // rotate to spread LDS banks
                    int j = (jj + tid) & 3;
                    Bs[(n4 + j) * BKP + k] = b4[j];
                }
            }
        }
        __syncthreads();
        // ---- fragments + MFMA ----
        s16x8 af[4], bf[4];
        #pragma unroll
        for (int mi = 0; mi < 4; ++mi)
            af[mi] = *(const s16x8*)&As[(wr * 64 + mi * 16 + lr) * BKP + kq * 8];
        #pragma unroll
        for (int ni = 0; ni < 4; ++ni)
            bf[ni] = *(const s16x8*)&Bs[(wc * 64 + ni * 16 + lr) * BKP + kq * 8];
        #pragma unroll
        for (int mi = 0; mi < 4; ++mi)
            #pragma unroll
            for (int ni = 0; ni < 4; ++ni)
                acc[mi][ni] = __builtin_amdgcn_mfma_f32_16x16x32_bf16(af[mi], bf[ni], acc[mi][ni], 0, 0, 0);
        __syncthreads();
    }
    // ---- epilogue: D row = (lane>>4)*4 + reg, col = lane&15 (m89-verified) ----
    #pragma unroll
    for (int mi = 0; mi < 4; ++mi) {
        #pragma unroll
        for (int ni = 0; ni < 4; ++ni) {
            int row = m0 + wr * 64 + mi * 16 + kq * 4;
            int col = n0 + wc * 64 + ni * 16 + lr;
            #pragma unroll
            for (int r = 0; r < 4; ++r) {
                int gr = row + r;
                if (gr < M && col < N) {
                    float v = acc[mi][ni][r];
                    if (bias) v += bias[col];
                    if (OUT_BF16) ((short*)C)[(size_t)gr * ldc + col] = f2bf(v);
                    else          ((float*)C)[(size_t)gr * ldc + col] = v;
                }
            }
        }
    }
}

extern "C" void kernel_launch(void* const* d_in, const int* in_sizes, int n_in,
                              void* d_out, int out_size, void* d_ws, size_t ws_size,
                              hipStream_t stream) {
    const int*   g_node_idx   = (const int*)d_in[0];
    const int*   g_edge_index = (const int*)d_in[1];
    const int*   g_center     = (const int*)d_in[2];
    const int*   u_eindex     = (const int*)d_in[3];
    const int*   anchors      = (const int*)d_in[4];
    const float* item_emb     = (const float*)d_in[5];
    const float* user_emb     = (const float*)d_in[6];
    const float* convs_W      = (const float*)d_in[7];
    const float* convs_as     = (const float*)d_in[8];
    const float* convs_ad     = (const float*)d_in[9];
    const float* convs_bias   = (const float*)d_in[10];
    const float* u_W          = (const float*)d_in[11];
    const float* u_as         = (const float*)d_in[12];
    const float* u_ad         = (const float*)d_in[13];
    const float* u_bias       = (const float*)d_in[14];
    const float* a_rw_W       = (const float*)d_in[15];
    const float* a_rw_b       = (const float*)d_in[16];
    const float* pp_stp_W     = (const float*)d_in[17];
    const float* pp_stp_b     = (const float*)d_in[18];
    const float* final_W      = (const float*)d_in[19];
    const float* final_b      = (const float*)d_in[20];

    // Scratch in d_out (51.2M floats); everything dead before the final GEMM
    // overwrites d_out. FRb (read during final GEMM) lives in d_ws.
    float* ob    = (float*)d_out;
    float* xa    = ob;                     // 20000*768 f32
    float* denom = ob + 15360000;          // 20000*256
    float* outun = ob + 20480000;          // 20000*256
    int*   masks = (int*)(ob + 25600000);  // 150000 ints
    short* sb    = (short*)(ob + 25750016);// bf16 region (16B aligned)
    short* item_embb = sb;                 // 6,400,000
    short* user_embb = sb + 6400000;       // 1,280,000
    short* Wcombb    = sb + 7680000;       // 786,432  (B^T per conv: [768][128])
    short* outsb     = sb + 8466432;       // 6*1024*256
    short* X1b       = sb + 10039296;      // 1024*512
    short* X2b       = sb + 10563584;      // 1024*512  [pp_x | stp]
    short* a_rw_Wb   = sb + 11087872;      // 256*512 (B^T)
    short* pp_stp_Wb = sb + 11218944;      // 256*512 (B^T)
    short* FRb       = (short*)d_ws;       // 1024*512  [y | u_x]

    dim3 blk(256);

    wcomb_kernel<<<3072, blk, 0, stream>>>(convs_W, convs_as, convs_ad, u_W, u_as, u_ad, Wcombb);
    conv_bf16_kernel<<<6250, blk, 0, stream>>>(item_emb, item_embb, 1600000);
    conv_bf16_kernel<<<1250, blk, 0, stream>>>(user_emb, user_embb, 320000);
    tconv_kernel<<<dim3(4, 8), blk, 0, stream>>>(a_rw_W, a_rw_Wb, 512, 256);
    tconv_kernel<<<dim3(4, 8), blk, 0, stream>>>(pp_stp_W, pp_stp_Wb, 512, 256);
    mask_zero_kernel<<<587, blk, 0, stream>>>(masks, 150000);
    mask_set_kernel<<<32, blk, 0, stream>>>(g_center, anchors, masks);

    for (int g = 0; g < NUM_G; ++g) {
        mgemm<true, false, false, false><<<dim3(6, 157), blk, 0, stream>>>(
            item_embb, g_node_idx + g * N_NODES, FIN,
            Wcombb + (size_t)g * NC * FIN, FIN, xa, NC, nullptr, N_NODES, NC, FIN);
        zero_rows_kernel<<<B_SZ, blk, 0, stream>>>(g_center + g * B_SZ, denom, outun);
        edge_kernel<<<E_EDGES / 4, blk, 0, stream>>>(
            g_edge_index + (size_t)g * 2 * E_EDGES,
            g_edge_index + (size_t)g * 2 * E_EDGES + E_EDGES,
            xa, masks + g * N_NODES, denom, outun, E_EDGES);
        short* dest = (g < 6) ? outsb + (size_t)g * B_SZ * HCC : X2b;  // g==6 -> X2[:, :256]
        int ldc = (g < 6) ? HCC : 512;
        finalize_kernel<<<B_SZ, blk, 0, stream>>>(
            g_center + g * B_SZ, denom, outun, convs_bias + g * HCC, dest, ldc);
    }

    // user graph conv (identity gather)
    mgemm<false, false, false, false><<<dim3(6, 79), blk, 0, stream>>>(
        user_embb, nullptr, FIN,
        Wcombb + (size_t)NUM_G * NC * FIN, FIN, xa, NC, nullptr, U_NODES, NC, FIN);
    zero_rows_kernel<<<B_SZ, blk, 0, stream>>>(anchors, denom, outun);
    edge_kernel<<<E_EDGES / 4, blk, 0, stream>>>(
        u_eindex, u_eindex + E_EDGES, xa, masks + NUM_G * N_NODES, denom, outun, E_EDGES);
    finalize_kernel<<<B_SZ, blk, 0, stream>>>(
        anchors, denom, outun, u_bias, FRb + 256, 512);               // u_x -> FR[:, 256:]

    avg_kernel<<<B_SZ, blk, 0, stream>>>(outsb, X1b);
    // stp = X1 @ a_rw_W + b -> X2[:, 256:]
    mgemm<false, true, false, false><<<dim3(2, 8), blk, 0, stream>>>(
        X1b, nullptr, 512, a_rw_Wb, 512, X2b + 256, 512, a_rw_b, B_SZ, HCC, 512);
    // y = X2 @ pp_stp_W + b -> FR[:, :256]
    mgemm<false, true, false, false><<<dim3(2, 8), blk, 0, stream>>>(
        X2b, nullptr, 512, pp_stp_Wb, 512, FRb, 512, pp_stp_b, B_SZ, HCC, 512);
    // logits = FR @ final_W + final_b -> d_out (f32 B staged inline; XCD swizzle)
    mgemm<false, false, true, true><<<dim3(8, 391), blk, 0, stream>>>(
        FRb, nullptr, 512, final_W, ITEMS, ob, ITEMS, final_b, B_SZ, ITEMS, 512);
}

// Round 4
// 1107.787 us; speedup vs baseline: 1.8427x; 1.1788x over previous
//
#include <hip/hip_runtime.h>
#include <hip/hip_bf16.h>
#include <cstdint>
#include <cstddef>

#define NUM_G   7
#define E_EDGES 100000
#define N_NODES 20000
#define U_NODES 10000
#define B_SZ    1024
#define HCC     256     // H*C
#define FIN     128
#define NC      768     // combined cols: [xh | a_src | a_dst]
#define ITEMS   50000

typedef float f32x4 __attribute__((ext_vector_type(4)));
typedef short s16x8 __attribute__((ext_vector_type(8)));

typedef const __attribute__((address_space(1))) void gvoid_t;
typedef __attribute__((address_space(3))) void lvoid_t;

// async global->LDS DMA, 16B per lane; LDS dest must be wave-uniform base + lane*16
__device__ inline void gld16(const void* g, void* l) {
    __builtin_amdgcn_global_load_lds((gvoid_t*)g, (lvoid_t*)l, 16, 0, 0);
}

__device__ inline short f2bf(float f) {              // RNE f32 -> bf16
    uint32_t x = __builtin_bit_cast(uint32_t, f);
    uint32_t r = (x + 0x7FFFu + ((x >> 16) & 1u)) >> 16;
    return (short)r;
}

// ---------------- Wcomb precompute -> bf16, B^T layout [conv][n=768][k=128] ----------
// Wse[k, h*64+d] = sum_c W[k, h*64+c] * att[h,c,d];  stored transposed for MFMA B-side.
__global__ void wcomb_kernel(const float* __restrict__ convs_W,
                             const float* __restrict__ convs_as,
                             const float* __restrict__ convs_ad,
                             const float* __restrict__ uW,
                             const float* __restrict__ u_as,
                             const float* __restrict__ u_ad,
                             short* __restrict__ Wcombb) {
    int gid = blockIdx.x * 256 + threadIdx.x;        // 8 * 768 * 128, i fastest
    int conv = gid / (NC * FIN);
    int rem  = gid % (NC * FIN);
    int j = rem / FIN, i = rem % FIN;                // j = output col (0..767), i = k (0..127)
    const float* W = (conv < NUM_G) ? convs_W + (size_t)conv * FIN * HCC : uW;
    float v;
    if (j < HCC) {
        v = W[i * HCC + j];
    } else {
        int which = (j - HCC) / HCC;                 // 0 = src, 1 = dst
        int jj = (j - HCC) % HCC;
        int h = jj / 64, d = jj % 64;
        const float* att;
        if (which == 0) att = (conv < NUM_G) ? convs_as + (size_t)conv * 4 * 64 * 64 : u_as;
        else            att = (conv < NUM_G) ? convs_ad + (size_t)conv * 4 * 64 * 64 : u_ad;
        att += h * 64 * 64;
        const float* wrow = W + i * HCC + h * 64;
        float s = 0.f;
        #pragma unroll 4
        for (int c = 0; c < 64; ++c) s += wrow[c] * att[c * 64 + d];
        v = s;
    }
    Wcombb[gid] = f2bf(v);
}

// ---------------- flat f32 -> bf16 convert (n4 = quads) ----------------
__global__ void conv_bf16_kernel(const float* __restrict__ in, short* __restrict__ out, int n4) {
    int i = blockIdx.x * 256 + threadIdx.x;
    if (i >= n4) return;
    float4 v = ((const float4*)in)[i];
    short4 o; o.x = f2bf(v.x); o.y = f2bf(v.y); o.z = f2bf(v.z); o.w = f2bf(v.w);
    *(short4*)&out[(size_t)i * 4] = o;
}

// ---------------- transpose+convert: f32 [K][N] -> bf16 [N][K], N guarded --------------
__global__ void tconv_kernel(const float* __restrict__ in, short* __restrict__ out, int K, int N) {
    __shared__ float t[64][65];
    int n0 = blockIdx.x * 64, k0 = blockIdx.y * 64;
    int r = threadIdx.x >> 4, c4 = (threadIdx.x & 15) * 4;
    #pragma unroll
    for (int rr = 0; rr < 4; ++rr) {
        int k = r + rr * 16;
        int gn = n0 + c4;
        float4 v = make_float4(0.f, 0.f, 0.f, 0.f);
        const float* bp = &in[(size_t)(k0 + k) * N + gn];
        if (gn + 3 < N) v = *(const float4*)bp;
        else {
            if (gn + 0 < N) v.x = bp[0];
            if (gn + 1 < N) v.y = bp[1];
            if (gn + 2 < N) v.z = bp[2];
        }
        *(float4*)&t[k][c4] = v;
    }
    __syncthreads();
    #pragma unroll
    for (int rr = 0; rr < 4; ++rr) {
        int n = r + rr * 16;
        if (n0 + n < N) {
            short4 o;
            o.x = f2bf(t[c4 + 0][n]); o.y = f2bf(t[c4 + 1][n]);
            o.z = f2bf(t[c4 + 2][n]); o.w = f2bf(t[c4 + 3][n]);
            *(short4*)&out[(size_t)(n0 + n) * K + k0 + c4] = o;
        }
    }
}

// ---------------- mask build ----------------
__global__ void mask_zero_kernel(int* __restrict__ m, int n) {
    int i = blockIdx.x * 256 + threadIdx.x;
    if (i < n) m[i] = 0;
}

__global__ void mask_set_kernel(const int* __restrict__ g_center,
                                const int* __restrict__ anchors,
                                int* __restrict__ masks) {
    int t = blockIdx.x * 256 + threadIdx.x;          // 8 * 1024 threads
    int conv = t / B_SZ, b = t % B_SZ;
    if (conv < NUM_G) masks[conv * N_NODES + g_center[conv * B_SZ + b]] = 1;
    else              masks[NUM_G * N_NODES + anchors[b]] = 1;
}

// ---------------- per-conv init: zero only the rows that receive atomics -------------
__global__ void zero_rows_kernel(const int* __restrict__ center,
                                 float* __restrict__ denom, float* __restrict__ outun) {
    int b = blockIdx.x; int c = threadIdx.x;         // grid B_SZ x 256
    int row = center[b];
    denom[(size_t)row * HCC + c] = 0.f;
    outun[(size_t)row * HCC + c] = 0.f;
}

// ---------------- edge pass: one wave per edge, skip non-center dst -------------------
__global__ void edge_kernel(const int* __restrict__ src, const int* __restrict__ dst,
                            const float* __restrict__ xa, const int* __restrict__ mask,
                            float* __restrict__ denom, float* __restrict__ outun, int E) {
    int w = threadIdx.x >> 6;
    int lane = threadIdx.x & 63;
    int e = blockIdx.x * 4 + w;
    if (e >= E) return;
    int d = dst[e];
    if (mask[d] == 0) return;                        // dst never read at centers -> skip
    int s = src[e];
    const float4* ps = (const float4*)(xa + (size_t)s * NC);
    const float4* pd = (const float4*)(xa + (size_t)d * NC);
    float4 xh = ps[lane];
    float4 as = ps[64 + lane];
    float4 ad = pd[128 + lane];
    float* dden = denom + (size_t)d * HCC + lane * 4;
    float* dout = outun + (size_t)d * HCC + lane * 4;
    float ev[4] = {as.x + ad.x, as.y + ad.y, as.z + ad.z, as.w + ad.w};
    float xv[4] = {xh.x, xh.y, xh.z, xh.w};
    #pragma unroll
    for (int j = 0; j < 4; ++j) {
        float t = ev[j];
        t = (t >= 0.f) ? t : 0.2f * t;               // leaky_relu, slope 0.2
        float p = expf(t);                           // emax shift cancels in the quotient
        atomicAdd(dden + j, p);
        atomicAdd(dout + j, p * xv[j]);
    }
}

// ---------------- finalize: gather at centers, normalize, + bias -> bf16 -------------
__global__ void finalize_kernel(const int* __restrict__ center,
                                const float* __restrict__ denom,
                                const float* __restrict__ outun,
                                const float* __restrict__ bias,
                                short* __restrict__ dest, int ldc) {
    int b = blockIdx.x; int c = threadIdx.x;         // grid B_SZ x 256
    int row = center[b];
    float v = outun[(size_t)row * HCC + c] / (denom[(size_t)row * HCC + c] + 1e-16f) + bias[c];
    dest[(size_t)b * ldc + c] = f2bf(v);
}

// ---------------- stp averaging (bf16 in/out) ----------------
__global__ void avg_kernel(const short* __restrict__ outs, short* __restrict__ X1) {
    int b = blockIdx.x, c = threadIdx.x;             // grid B_SZ x 256
    size_t off = (size_t)b * HCC + c;
    const size_t S = (size_t)B_SZ * HCC;
    auto ld = [](short s) { return __builtin_bit_cast(float, (uint32_t)(unsigned short)s << 16); };
    float v1 = (ld(outs[off]) + ld(outs[S + off]) + ld(outs[2 * S + off])) / 3.0f;
    float v2 = (ld(outs[3 * S + off]) + ld(outs[4 * S + off]) + ld(outs[5 * S + off])) / 3.0f;
    X1[(size_t)b * 512 + c] = f2bf(v1);
    X1[(size_t)b * 512 + 256 + c] = f2bf(v2);
}

// ---------------- bf16 MFMA GEMM, global_load_lds staging ----------------
// C[M,N](f32 or bf16) = gatherA[M,K](bf16) @ B (+bias).
// B: bf16 B^T [N][ldb] (BF32=false, DMA-staged) or f32 [K][ldb] row-major (BF32=true,
// reg-converted fallback). BM=BN=128, BK=32, 256 thr = 4 waves (2x2), wave tile 64x64.
// LDS layout LINEAR [128][32] bf16 (gload_lds requires it); full-span b128 fragment
// reads are bank-optimal without padding.
template<bool GATHER, bool OUT_BF16, bool BF32, bool SWZ>
__launch_bounds__(256)
__global__ void mgemm(const short* __restrict__ A, const int* __restrict__ idx, int lda,
                      const void* __restrict__ Bv, int ldb,
                      void* __restrict__ C, int ldc, const float* __restrict__ bias,
                      int M, int N, int K) {
    __shared__ __align__(16) short As[128 * 32];
    __shared__ __align__(16) short Bs[128 * 32];
    int tid = threadIdx.x;
    int lane = tid & 63, w = tid >> 6;
    int wr = w >> 1, wc = w & 1;
    int lr = lane & 15, kq = lane >> 4;
    int m0, n0;
    if (SWZ) {                                       // XCD-chunked: requires gridDim.x==8
        int b = blockIdx.x + (blockIdx.y << 3);
        int L = (b & 7) * gridDim.y + (b >> 3);      // XCD k owns a contiguous L-range
        m0 = (L & 7) * 128;
        n0 = (L >> 3) * 128;
    } else {
        m0 = blockIdx.y * 128; n0 = blockIdx.x * 128;
    }

    f32x4 acc[4][4];
    #pragma unroll
    for (int i = 0; i < 4; ++i)
        #pragma unroll
        for (int j = 0; j < 4; ++j)
            #pragma unroll
            for (int r = 0; r < 4; ++r) acc[i][j][r] = 0.f;

    // hoisted per-thread staging coords; thread c stages row r=c>>2, chunk (c&3)*8
    // LDS dest byte = c*16  (linear in tid -> wave-uniform base + lane*16)
    const short* asrc[2]; bool aok[2];
    const short* bsrc[2]; bool bok[2];
    #pragma unroll
    for (int it = 0; it < 2; ++it) {
        int c = tid + it * 256;
        int r = c >> 2, k8 = (c & 3) * 8;
        int gr = m0 + r;
        aok[it] = gr < M;
        long ar = aok[it] ? (GATHER ? (long)idx[gr] : (long)gr) : 0;
        asrc[it] = A + ar * lda + k8;
        int gn = n0 + r;
        bok[it] = gn < N;
        if constexpr (!BF32)
            bsrc[it] = (const short*)Bv + (long)(bok[it] ? gn : 0) * ldb + k8;
        else
            bsrc[it] = nullptr;
    }

    for (int kb = 0; kb < K; kb += 32) {
        // ---- stage A via DMA (skipped lanes leave garbage rows >= M; never stored) ----
        #pragma unroll
        for (int it = 0; it < 2; ++it)
            if (aok[it]) gld16(asrc[it] + kb, &As[(tid + it * 256) * 8]);
        if constexpr (!BF32) {
            #pragma unroll
            for (int it = 0; it < 2; ++it)
                if (bok[it]) gld16(bsrc[it] + kb, &Bs[(tid + it * 256) * 8]);
        } else {
            // fallback: f32 B row-major, convert in regs, scalar LDS writes
            const float* Bf = (const float*)Bv;
            #pragma unroll
            for (int it = 0; it < 4; ++it) {
                int c = tid + it * 256;              // 1024 float4-chunks of 32x128 tile
                int k = c >> 5, n4 = (c & 31) * 4;
                int gn = n0 + n4;
                float4 v = make_float4(0.f, 0.f, 0.f, 0.f);
                const float* bp = &Bf[(size_t)(kb + k) * ldb + gn];
                if (gn + 3 < N) v = *(const float4*)bp;
                else {
                    if (gn + 0 < N) v.x = bp[0];
                    if (gn + 1 < N) v.y = bp[1];
                    if (gn + 2 < N) v.z = bp[2];
                    if (gn + 3 < N) v.w = bp[3];
                }
                short b4[4] = {f2bf(v.x), f2bf(v.y), f2bf(v.z), f2bf(v.w)};
                #pragma unroll
                for (int jj = 0; jj < 4; ++jj) {     // rotate to spread LDS banks
                    int j = (jj + tid) & 3;
                    Bs[(n4 + j) * 32 + k] = b4[j];
                }
            }
        }
        __syncthreads();                             // drains vmcnt + lgkmcnt
        // ---- fragments + MFMA ----
        s16x8 af[4], bf[4];
        #pragma unroll
        for (int mi = 0; mi < 4; ++mi)
            af[mi] = *(const s16x8*)&As[(wr * 64 + mi * 16 + lr) * 32 + kq * 8];
        #pragma unroll
        for (int ni = 0; ni < 4; ++ni)
            bf[ni] = *(const s16x8*)&Bs[(wc * 64 + ni * 16 + lr) * 32 + kq * 8];
        #pragma unroll
        for (int mi = 0; mi < 4; ++mi)
            #pragma unroll
            for (int ni = 0; ni < 4; ++ni)
                acc[mi][ni] = __builtin_amdgcn_mfma_f32_16x16x32_bf16(af[mi], bf[ni], acc[mi][ni], 0, 0, 0);
        __syncthreads();
    }
    // ---- epilogue: D row = (lane>>4)*4 + reg, col = lane&15 (m89-verified) ----
    #pragma unroll
    for (int mi = 0; mi < 4; ++mi) {
        #pragma unroll
        for (int ni = 0; ni < 4; ++ni) {
            int row = m0 + wr * 64 + mi * 16 + kq * 4;
            int col = n0 + wc * 64 + ni * 16 + lr;
            #pragma unroll
            for (int r = 0; r < 4; ++r) {
                int gr = row + r;
                if (gr < M && col < N) {
                    float v = acc[mi][ni][r];
                    if (bias) v += bias[col];
                    if (OUT_BF16) ((short*)C)[(size_t)gr * ldc + col] = f2bf(v);
                    else          ((float*)C)[(size_t)gr * ldc + col] = v;
                }
            }
        }
    }
}

extern "C" void kernel_launch(void* const* d_in, const int* in_sizes, int n_in,
                              void* d_out, int out_size, void* d_ws, size_t ws_size,
                              hipStream_t stream) {
    const int*   g_node_idx   = (const int*)d_in[0];
    const int*   g_edge_index = (const int*)d_in[1];
    const int*   g_center     = (const int*)d_in[2];
    const int*   u_eindex     = (const int*)d_in[3];
    const int*   anchors      = (const int*)d_in[4];
    const float* item_emb     = (const float*)d_in[5];
    const float* user_emb     = (const float*)d_in[6];
    const float* convs_W      = (const float*)d_in[7];
    const float* convs_as     = (const float*)d_in[8];
    const float* convs_ad     = (const float*)d_in[9];
    const float* convs_bias   = (const float*)d_in[10];
    const float* u_W          = (const float*)d_in[11];
    const float* u_as         = (const float*)d_in[12];
    const float* u_ad         = (const float*)d_in[13];
    const float* u_bias       = (const float*)d_in[14];
    const float* a_rw_W       = (const float*)d_in[15];
    const float* a_rw_b       = (const float*)d_in[16];
    const float* pp_stp_W     = (const float*)d_in[17];
    const float* pp_stp_b     = (const float*)d_in[18];
    const float* final_W      = (const float*)d_in[19];
    const float* final_b      = (const float*)d_in[20];

    // Scratch in d_out (51.2M floats); everything dead before the final GEMM
    // overwrites d_out. Data read DURING the final GEMM (FRb, final_Wb) lives in d_ws.
    float* ob    = (float*)d_out;
    float* xa    = ob;                     // 20000*768 f32
    float* denom = ob + 15360000;          // 20000*256
    float* outun = ob + 20480000;          // 20000*256
    int*   masks = (int*)(ob + 25600000);  // 150000 ints
    short* sb    = (short*)(ob + 25750016);// bf16 region (16B aligned)
    short* item_embb = sb;                 // 6,400,000
    short* user_embb = sb + 6400000;       // 1,280,000
    short* Wcombb    = sb + 7680000;       // 786,432  (B^T per conv: [768][128])
    short* outsb     = sb + 8466432;       // 6*1024*256
    short* X1b       = sb + 10039296;      // 1024*512
    short* X2b       = sb + 10563584;      // 1024*512  [pp_x | stp]
    short* a_rw_Wb   = sb + 11087872;      // 256*512 (B^T)
    short* pp_stp_Wb = sb + 11218944;      // 256*512 (B^T)
    short* FRb       = (short*)d_ws;       // 1024*512  [y | u_x]
    short* final_Wb  = (short*)((char*)d_ws + 1048576);  // 50000*512 B^T bf16 (if ws fits)
    const size_t WS_NEED = 1048576 + (size_t)50048 * 512 * 2;
    const bool ws_fast = ws_size >= WS_NEED;   // deterministic per harness -> capture-safe

    dim3 blk(256);

    wcomb_kernel<<<3072, blk, 0, stream>>>(convs_W, convs_as, convs_ad, u_W, u_as, u_ad, Wcombb);
    conv_bf16_kernel<<<6250, blk, 0, stream>>>(item_emb, item_embb, 1600000);
    conv_bf16_kernel<<<1250, blk, 0, stream>>>(user_emb, user_embb, 320000);
    tconv_kernel<<<dim3(4, 8), blk, 0, stream>>>(a_rw_W, a_rw_Wb, 512, 256);
    tconv_kernel<<<dim3(4, 8), blk, 0, stream>>>(pp_stp_W, pp_stp_Wb, 512, 256);
    if (ws_fast)   // final_W [512][50000] -> bf16 B^T [50000][512] in d_ws
        tconv_kernel<<<dim3(782, 8), blk, 0, stream>>>(final_W, final_Wb, 512, ITEMS);
    mask_zero_kernel<<<587, blk, 0, stream>>>(masks, 150000);
    mask_set_kernel<<<32, blk, 0, stream>>>(g_center, anchors, masks);

    for (int g = 0; g < NUM_G; ++g) {
        mgemm<true, false, false, false><<<dim3(6, 157), blk, 0, stream>>>(
            item_embb, g_node_idx + g * N_NODES, FIN,
            Wcombb + (size_t)g * NC * FIN, FIN, xa, NC, nullptr, N_NODES, NC, FIN);
        zero_rows_kernel<<<B_SZ, blk, 0, stream>>>(g_center + g * B_SZ, denom, outun);
        edge_kernel<<<E_EDGES / 4, blk, 0, stream>>>(
            g_edge_index + (size_t)g * 2 * E_EDGES,
            g_edge_index + (size_t)g * 2 * E_EDGES + E_EDGES,
            xa, masks + g * N_NODES, denom, outun, E_EDGES);
        short* dest = (g < 6) ? outsb + (size_t)g * B_SZ * HCC : X2b;  // g==6 -> X2[:, :256]
        int ldc = (g < 6) ? HCC : 512;
        finalize_kernel<<<B_SZ, blk, 0, stream>>>(
            g_center + g * B_SZ, denom, outun, convs_bias + g * HCC, dest, ldc);
    }

    // user graph conv (identity gather)
    mgemm<false, false, false, false><<<dim3(6, 79), blk, 0, stream>>>(
        user_embb, nullptr, FIN,
        Wcombb + (size_t)NUM_G * NC * FIN, FIN, xa, NC, nullptr, U_NODES, NC, FIN);
    zero_rows_kernel<<<B_SZ, blk, 0, stream>>>(anchors, denom, outun);
    edge_kernel<<<E_EDGES / 4, blk, 0, stream>>>(
        u_eindex, u_eindex + E_EDGES, xa, masks + NUM_G * N_NODES, denom, outun, E_EDGES);
    finalize_kernel<<<B_SZ, blk, 0, stream>>>(
        anchors, denom, outun, u_bias, FRb + 256, 512);               // u_x -> FR[:, 256:]

    avg_kernel<<<B_SZ, blk, 0, stream>>>(outsb, X1b);
    // stp = X1 @ a_rw_W + b -> X2[:, 256:]
    mgemm<false, true, false, false><<<dim3(2, 8), blk, 0, stream>>>(
        X1b, nullptr, 512, a_rw_Wb, 512, X2b + 256, 512, a_rw_b, B_SZ, HCC, 512);
    // y = X2 @ pp_stp_W + b -> FR[:, :256]
    mgemm<false, true, false, false><<<dim3(2, 8), blk, 0, stream>>>(
        X2b, nullptr, 512, pp_stp_Wb, 512, FRb, 512, pp_stp_b, B_SZ, HCC, 512);
    // logits = FR @ final_W + final_b -> d_out (overwrites all d_out scratch)
    if (ws_fast)
        mgemm<false, false, false, true><<<dim3(8, 391), blk, 0, stream>>>(
            FRb, nullptr, 512, final_Wb, 512, ob, ITEMS, final_b, B_SZ, ITEMS, 512);
    else
        mgemm<false, false, true, true><<<dim3(8, 391), blk, 0, stream>>>(
            FRb, nullptr, 512, final_W, ITEMS, ob, ITEMS, final_b, B_SZ, ITEMS, 512);
}

// Round 5
// 800.160 us; speedup vs baseline: 2.5511x; 1.3845x over previous
//
#include <hip/hip_runtime.h>
#include <hip/hip_bf16.h>
#include <cstdint>
#include <cstddef>

#define NUM_G   7
#define E_EDGES 100000
#define N_NODES 20000
#define U_NODES 10000
#define B_SZ    1024
#define HCC     256     // H*C
#define FIN     128
#define NC      768     // combined cols: [xh | a_src | a_dst]
#define ITEMS   50000
#define NGRAPH  8       // 7 item graphs + user graph
#define SLOTS   (NGRAPH * B_SZ)
#define INF_I   0x7fffffff

typedef float f32x4 __attribute__((ext_vector_type(4)));
typedef short s16x8 __attribute__((ext_vector_type(8)));

typedef const __attribute__((address_space(1))) void gvoid_t;
typedef __attribute__((address_space(3))) void lvoid_t;

// async global->LDS DMA, 16B per lane; LDS dest must be wave-uniform base + lane*16
__device__ inline void gld16(const void* g, void* l) {
    __builtin_amdgcn_global_load_lds((gvoid_t*)g, (lvoid_t*)l, 16, 0, 0);
}

__device__ inline short f2bf(float f) {              // RNE f32 -> bf16
    uint32_t x = __builtin_bit_cast(uint32_t, f);
    uint32_t r = (x + 0x7FFFu + ((x >> 16) & 1u)) >> 16;
    return (short)r;
}

// ---------------- Wcomb precompute -> bf16, B^T layout [conv][n=768][k=128] ----------
__global__ void wcomb_kernel(const float* __restrict__ convs_W,
                             const float* __restrict__ convs_as,
                             const float* __restrict__ convs_ad,
                             const float* __restrict__ uW,
                             const float* __restrict__ u_as,
                             const float* __restrict__ u_ad,
                             short* __restrict__ Wcombb) {
    int gid = blockIdx.x * 256 + threadIdx.x;        // 8 * 768 * 128, i fastest
    int conv = gid / (NC * FIN);
    int rem  = gid % (NC * FIN);
    int j = rem / FIN, i = rem % FIN;                // j = output col, i = k
    const float* W = (conv < NUM_G) ? convs_W + (size_t)conv * FIN * HCC : uW;
    float v;
    if (j < HCC) {
        v = W[i * HCC + j];
    } else {
        int which = (j - HCC) / HCC;                 // 0 = src, 1 = dst
        int jj = (j - HCC) % HCC;
        int h = jj / 64, d = jj % 64;
        const float* att;
        if (which == 0) att = (conv < NUM_G) ? convs_as + (size_t)conv * 4 * 64 * 64 : u_as;
        else            att = (conv < NUM_G) ? convs_ad + (size_t)conv * 4 * 64 * 64 : u_ad;
        att += h * 64 * 64;
        const float* wrow = W + i * HCC + h * 64;
        float s = 0.f;
        #pragma unroll 4
        for (int c = 0; c < 64; ++c) s += wrow[c] * att[c * 64 + d];
        v = s;
    }
    Wcombb[gid] = f2bf(v);
}

// ---------------- flat f32 -> bf16 convert (n4 = quads) ----------------
__global__ void conv_bf16_kernel(const float* __restrict__ in, short* __restrict__ out, int n4) {
    int i = blockIdx.x * 256 + threadIdx.x;
    if (i >= n4) return;
    float4 v = ((const float4*)in)[i];
    short4 o; o.x = f2bf(v.x); o.y = f2bf(v.y); o.z = f2bf(v.z); o.w = f2bf(v.w);
    *(short4*)&out[(size_t)i * 4] = o;
}

// ---------------- transpose+convert: f32 [K][N] -> bf16 [N][K], N guarded --------------
__global__ void tconv_kernel(const float* __restrict__ in, short* __restrict__ out, int K, int N) {
    __shared__ float t[64][65];
    int n0 = blockIdx.x * 64, k0 = blockIdx.y * 64;
    int r = threadIdx.x >> 4, c4 = (threadIdx.x & 15) * 4;
    #pragma unroll
    for (int rr = 0; rr < 4; ++rr) {
        int k = r + rr * 16;
        int gn = n0 + c4;
        float4 v = make_float4(0.f, 0.f, 0.f, 0.f);
        const float* bp = &in[(size_t)(k0 + k) * N + gn];
        if (gn + 3 < N) v = *(const float4*)bp;
        else {
            if (gn + 0 < N) v.x = bp[0];
            if (gn + 1 < N) v.y = bp[1];
            if (gn + 2 < N) v.z = bp[2];
        }
        *(float4*)&t[k][c4] = v;
    }
    __syncthreads();
    #pragma unroll
    for (int rr = 0; rr < 4; ++rr) {
        int n = r + rr * 16;
        if (n0 + n < N) {
            short4 o;
            o.x = f2bf(t[c4 + 0][n]); o.y = f2bf(t[c4 + 1][n]);
            o.z = f2bf(t[c4 + 2][n]); o.w = f2bf(t[c4 + 3][n]);
            *(short4*)&out[(size_t)(n0 + n) * K + k0 + c4] = o;
        }
    }
}

// ================= edge-phase prep (all 8 graphs, atomic-light) =================
// remapC[g][node] = min center-slot with that node (INF if not a center).
__global__ void prep_kernel(int* __restrict__ remapC, int* __restrict__ cnt,
                            int* __restrict__ fill) {
    int i = blockIdx.x * 256 + threadIdx.x;          // 625 blocks = 160000 threads
    remapC[i] = INF_I;
    if (i < SLOTS) { cnt[i] = 0; fill[i] = 0; }
}

__global__ void center_map_kernel(const int* __restrict__ g_center,
                                  const int* __restrict__ anchors,
                                  int* __restrict__ remapC) {
    int t = blockIdx.x * 256 + threadIdx.x;          // 32 blocks = 8192
    int g = t / B_SZ, b = t % B_SZ;
    int node = (g < NUM_G) ? g_center[g * B_SZ + b] : anchors[b];
    atomicMin(&remapC[g * N_NODES + node], b);
}

// count surviving edges per canonical center slot
__global__ void scan_kernel(const int* __restrict__ g_edge_index,
                            const int* __restrict__ u_eindex,
                            const int* __restrict__ remapC, int* __restrict__ cnt) {
    int t = blockIdx.x * 256 + threadIdx.x;          // 3125 blocks = 800000
    int g = t / E_EDGES, e = t % E_EDGES;
    const int* ei = (g < NUM_G) ? g_edge_index + (size_t)g * 2 * E_EDGES : u_eindex;
    int d = ei[E_EDGES + e];
    int slot = remapC[g * N_NODES + d];
    if (slot != INF_I) atomicAdd(&cnt[g * B_SZ + slot], 1);
}

// exclusive prefix over 8192 counts; 1 block, 256 threads x 32 elems
__global__ void scan_offs_kernel(const int* __restrict__ cnt, int* __restrict__ offs) {
    __shared__ int ps[256];
    int t = threadIdx.x;
    int base = t * 32, s = 0;
    int loc[32];
    #pragma unroll
    for (int i = 0; i < 32; ++i) { loc[i] = s; s += cnt[base + i]; }
    ps[t] = s; __syncthreads();
    for (int off = 1; off < 256; off <<= 1) {
        int v = (t >= off) ? ps[t - off] : 0;
        __syncthreads();
        ps[t] += v;
        __syncthreads();
    }
    int pre = (t == 0) ? 0 : ps[t - 1];
    #pragma unroll
    for (int i = 0; i < 32; ++i) offs[base + i] = pre + loc[i];
    if (t == 255) offs[SLOTS] = pre + s;
}

// scatter surviving edges' src into per-slot buckets
__global__ void fill_kernel(const int* __restrict__ g_edge_index,
                            const int* __restrict__ u_eindex,
                            const int* __restrict__ remapC,
                            const int* __restrict__ offs, int* __restrict__ fill,
                            int* __restrict__ elist) {
    int t = blockIdx.x * 256 + threadIdx.x;          // 3125 blocks
    int g = t / E_EDGES, e = t % E_EDGES;
    const int* ei = (g < NUM_G) ? g_edge_index + (size_t)g * 2 * E_EDGES : u_eindex;
    int d = ei[E_EDGES + e];
    int slot = remapC[g * N_NODES + d];
    if (slot != INF_I) {
        int pos = offs[g * B_SZ + slot] + atomicAdd(&fill[g * B_SZ + slot], 1);
        elist[pos] = ei[e];
    }
}

// ---------------- per-graph gather-aggregate: 1 wave per center slot ----------------
// out[b] = sum_j p_j*xh[src_j] / (sum_j p_j + 1e-16) + bias;  p = exp(lrelu(a_src+a_dst))
// (softmax max-shift cancels in the quotient). Atomic-free; deg~5 sequential iters.
__global__ void aggregate_kernel(const int* __restrict__ center,   // this graph's centers
                                 const int* __restrict__ remapC,   // + g*N_NODES
                                 const int* __restrict__ cnt,      // + g*B_SZ
                                 const int* __restrict__ offs,     // + g*B_SZ
                                 const int* __restrict__ elist,
                                 const float* __restrict__ xa,
                                 const float* __restrict__ bias,
                                 short* __restrict__ dest, int ldc) {
    int w = threadIdx.x >> 6, lane = threadIdx.x & 63;
    int s = blockIdx.x * 4 + w;                      // slot 0..1023 (grid 256 x 4 waves)
    int node = center[s];
    int c = remapC[node];                            // canonical slot (<= s)
    int o = offs[c], deg = cnt[c];
    f32x4 ad = *(const f32x4*)&xa[(size_t)node * NC + 512 + lane * 4];
    f32x4 den = {0.f, 0.f, 0.f, 0.f}, num = {0.f, 0.f, 0.f, 0.f};
    for (int j = 0; j < deg; ++j) {
        int sid = elist[o + j];
        f32x4 xh = *(const f32x4*)&xa[(size_t)sid * NC + lane * 4];
        f32x4 as = *(const f32x4*)&xa[(size_t)sid * NC + 256 + lane * 4];
        #pragma unroll
        for (int q = 0; q < 4; ++q) {
            float t = as[q] + ad[q];
            t = (t >= 0.f) ? t : 0.2f * t;           // leaky_relu 0.2
            float p = __expf(t);
            den[q] += p;
            num[q] += p * xh[q];
        }
    }
    #pragma unroll
    for (int q = 0; q < 4; ++q) {
        int ch = lane * 4 + q;
        float v = num[q] / (den[q] + 1e-16f) + bias[ch];
        dest[(size_t)s * ldc + ch] = f2bf(v);
    }
}

// ---------------- stp averaging (bf16 in/out) ----------------
__global__ void avg_kernel(const short* __restrict__ outs, short* __restrict__ X1) {
    int b = blockIdx.x, c = threadIdx.x;             // grid B_SZ x 256
    size_t off = (size_t)b * HCC + c;
    const size_t S = (size_t)B_SZ * HCC;
    auto ld = [](short s) { return __builtin_bit_cast(float, (uint32_t)(unsigned short)s << 16); };
    float v1 = (ld(outs[off]) + ld(outs[S + off]) + ld(outs[2 * S + off])) / 3.0f;
    float v2 = (ld(outs[3 * S + off]) + ld(outs[4 * S + off]) + ld(outs[5 * S + off])) / 3.0f;
    X1[(size_t)b * 512 + c] = f2bf(v1);
    X1[(size_t)b * 512 + 256 + c] = f2bf(v2);
}

// ---------------- bf16 MFMA GEMM, global_load_lds staging ----------------
template<bool GATHER, bool OUT_BF16, bool BF32, bool SWZ>
__launch_bounds__(256)
__global__ void mgemm(const short* __restrict__ A, const int* __restrict__ idx, int lda,
                      const void* __restrict__ Bv, int ldb,
                      void* __restrict__ C, int ldc, const float* __restrict__ bias,
                      int M, int N, int K) {
    __shared__ __align__(16) short As[128 * 32];
    __shared__ __align__(16) short Bs[128 * 32];
    int tid = threadIdx.x;
    int lane = tid & 63, w = tid >> 6;
    int wr = w >> 1, wc = w & 1;
    int lr = lane & 15, kq = lane >> 4;
    int m0, n0;
    if (SWZ) {                                       // XCD-chunked: requires gridDim.x==8
        int b = blockIdx.x + (blockIdx.y << 3);
        int L = (b & 7) * gridDim.y + (b >> 3);
        m0 = (L & 7) * 128;
        n0 = (L >> 3) * 128;
    } else {
        m0 = blockIdx.y * 128; n0 = blockIdx.x * 128;
    }

    f32x4 acc[4][4];
    #pragma unroll
    for (int i = 0; i < 4; ++i)
        #pragma unroll
        for (int j = 0; j < 4; ++j)
            #pragma unroll
            for (int r = 0; r < 4; ++r) acc[i][j][r] = 0.f;

    const short* asrc[2]; bool aok[2];
    const short* bsrc[2]; bool bok[2];
    #pragma unroll
    for (int it = 0; it < 2; ++it) {
        int c = tid + it * 256;
        int r = c >> 2, k8 = (c & 3) * 8;
        int gr = m0 + r;
        aok[it] = gr < M;
        long ar = aok[it] ? (GATHER ? (long)idx[gr] : (long)gr) : 0;
        asrc[it] = A + ar * lda + k8;
        int gn = n0 + r;
        bok[it] = gn < N;
        if constexpr (!BF32)
            bsrc[it] = (const short*)Bv + (long)(bok[it] ? gn : 0) * ldb + k8;
        else
            bsrc[it] = nullptr;
    }

    for (int kb = 0; kb < K; kb += 32) {
        #pragma unroll
        for (int it = 0; it < 2; ++it)
            if (aok[it]) gld16(asrc[it] + kb, &As[(tid + it * 256) * 8]);
        if constexpr (!BF32) {
            #pragma unroll
            for (int it = 0; it < 2; ++it)
                if (bok[it]) gld16(bsrc[it] + kb, &Bs[(tid + it * 256) * 8]);
        } else {
            const float* Bf = (const float*)Bv;
            #pragma unroll
            for (int it = 0; it < 4; ++it) {
                int c = tid + it * 256;
                int k = c >> 5, n4 = (c & 31) * 4;
                int gn = n0 + n4;
                float4 v = make_float4(0.f, 0.f, 0.f, 0.f);
                const float* bp = &Bf[(size_t)(kb + k) * ldb + gn];
                if (gn + 3 < N) v = *(const float4*)bp;
                else {
                    if (gn + 0 < N) v.x = bp[0];
                    if (gn + 1 < N) v.y = bp[1];
                    if (gn + 2 < N) v.z = bp[2];
                    if (gn + 3 < N) v.w = bp[3];
                }
                short b4[4] = {f2bf(v.x), f2bf(v.y), f2bf(v.z), f2bf(v.w)};
                #pragma unroll
                for (int jj = 0; jj < 4; ++jj) {
                    int j = (jj + tid) & 3;
                    Bs[(n4 + j) * 32 + k] = b4[j];
                }
            }
        }
        __syncthreads();
        s16x8 af[4], bf[4];
        #pragma unroll
        for (int mi = 0; mi < 4; ++mi)
            af[mi] = *(const s16x8*)&As[(wr * 64 + mi * 16 + lr) * 32 + kq * 8];
        #pragma unroll
        for (int ni = 0; ni < 4; ++ni)
            bf[ni] = *(const s16x8*)&Bs[(wc * 64 + ni * 16 + lr) * 32 + kq * 8];
        #pragma unroll
        for (int mi = 0; mi < 4; ++mi)
            #pragma unroll
            for (int ni = 0; ni < 4; ++ni)
                acc[mi][ni] = __builtin_amdgcn_mfma_f32_16x16x32_bf16(af[mi], bf[ni], acc[mi][ni], 0, 0, 0);
        __syncthreads();
    }
    #pragma unroll
    for (int mi = 0; mi < 4; ++mi) {
        #pragma unroll
        for (int ni = 0; ni < 4; ++ni) {
            int row = m0 + wr * 64 + mi * 16 + kq * 4;
            int col = n0 + wc * 64 + ni * 16 + lr;
            #pragma unroll
            for (int r = 0; r < 4; ++r) {
                int gr = row + r;
                if (gr < M && col < N) {
                    float v = acc[mi][ni][r];
                    if (bias) v += bias[col];
                    if (OUT_BF16) ((short*)C)[(size_t)gr * ldc + col] = f2bf(v);
                    else          ((float*)C)[(size_t)gr * ldc + col] = v;
                }
            }
        }
    }
}

extern "C" void kernel_launch(void* const* d_in, const int* in_sizes, int n_in,
                              void* d_out, int out_size, void* d_ws, size_t ws_size,
                              hipStream_t stream) {
    const int*   g_node_idx   = (const int*)d_in[0];
    const int*   g_edge_index = (const int*)d_in[1];
    const int*   g_center     = (const int*)d_in[2];
    const int*   u_eindex     = (const int*)d_in[3];
    const int*   anchors      = (const int*)d_in[4];
    const float* item_emb     = (const float*)d_in[5];
    const float* user_emb     = (const float*)d_in[6];
    const float* convs_W      = (const float*)d_in[7];
    const float* convs_as     = (const float*)d_in[8];
    const float* convs_ad     = (const float*)d_in[9];
    const float* convs_bias   = (const float*)d_in[10];
    const float* u_W          = (const float*)d_in[11];
    const float* u_as         = (const float*)d_in[12];
    const float* u_ad         = (const float*)d_in[13];
    const float* u_bias       = (const float*)d_in[14];
    const float* a_rw_W       = (const float*)d_in[15];
    const float* a_rw_b       = (const float*)d_in[16];
    const float* pp_stp_W     = (const float*)d_in[17];
    const float* pp_stp_b     = (const float*)d_in[18];
    const float* final_W      = (const float*)d_in[19];
    const float* final_b      = (const float*)d_in[20];

    // Scratch in d_out (51.2M floats); all dead before the final GEMM overwrites
    // d_out. Data read DURING the final GEMM (FRb, final_Wb) lives in d_ws.
    float* ob     = (float*)d_out;
    float* xa     = ob;                      // 20000*768 f32 (reused per graph)
    int*   remapC = (int*)(ob + 15360000);   // 8*20000
    int*   cnt    = remapC + 160000;         // 8192
    int*   offs   = cnt + SLOTS;             // 8193
    int*   fill   = offs + SLOTS + 1;        // 8192
    int*   elist  = fill + SLOTS;            // up to 800000
    short* sb     = (short*)(ob + 16400000); // bf16 region (16B aligned)
    short* item_embb = sb;                   // 6,400,000
    short* user_embb = sb + 6400000;         // 1,280,000
    short* Wcombb    = sb + 7680000;         // 786,432  (B^T per conv: [768][128])
    short* outsb     = sb + 8466432;         // 6*1024*256
    short* X1b       = sb + 10039296;        // 1024*512
    short* X2b       = sb + 10563584;        // 1024*512  [pp_x | stp]
    short* a_rw_Wb   = sb + 11087872;        // 256*512 (B^T)
    short* pp_stp_Wb = sb + 11218944;        // 256*512 (B^T)
    short* FRb       = (short*)d_ws;         // 1024*512  [y | u_x]
    short* final_Wb  = (short*)((char*)d_ws + 1048576);  // 50000*512 B^T bf16
    const size_t WS_NEED = 1048576 + (size_t)50048 * 512 * 2;
    const bool ws_fast = ws_size >= WS_NEED; // deterministic -> capture-safe

    dim3 blk(256);

    // --- weight/emb preprocessing ---
    wcomb_kernel<<<3072, blk, 0, stream>>>(convs_W, convs_as, convs_ad, u_W, u_as, u_ad, Wcombb);
    conv_bf16_kernel<<<6250, blk, 0, stream>>>(item_emb, item_embb, 1600000);
    conv_bf16_kernel<<<1250, blk, 0, stream>>>(user_emb, user_embb, 320000);
    tconv_kernel<<<dim3(4, 8), blk, 0, stream>>>(a_rw_W, a_rw_Wb, 512, 256);
    tconv_kernel<<<dim3(4, 8), blk, 0, stream>>>(pp_stp_W, pp_stp_Wb, 512, 256);
    if (ws_fast)
        tconv_kernel<<<dim3(782, 8), blk, 0, stream>>>(final_W, final_Wb, 512, ITEMS);

    // --- edge-phase prep for all 8 graphs (CSR buckets per center slot) ---
    prep_kernel<<<625, blk, 0, stream>>>(remapC, cnt, fill);
    center_map_kernel<<<32, blk, 0, stream>>>(g_center, anchors, remapC);
    scan_kernel<<<3125, blk, 0, stream>>>(g_edge_index, u_eindex, remapC, cnt);
    scan_offs_kernel<<<1, blk, 0, stream>>>(cnt, offs);
    fill_kernel<<<3125, blk, 0, stream>>>(g_edge_index, u_eindex, remapC, offs, fill, elist);

    // --- per-graph: gathered GEMM -> gather-aggregate (atomic-free) ---
    for (int g = 0; g < NUM_G; ++g) {
        mgemm<true, false, false, false><<<dim3(6, 157), blk, 0, stream>>>(
            item_embb, g_node_idx + g * N_NODES, FIN,
            Wcombb + (size_t)g * NC * FIN, FIN, xa, NC, nullptr, N_NODES, NC, FIN);
        short* dest = (g < 6) ? outsb + (size_t)g * B_SZ * HCC : X2b;  // g==6 -> X2[:, :256]
        int ldc = (g < 6) ? HCC : 512;
        aggregate_kernel<<<256, blk, 0, stream>>>(
            g_center + g * B_SZ, remapC + g * N_NODES, cnt + g * B_SZ, offs + g * B_SZ,
            elist, xa, convs_bias + g * HCC, dest, ldc);
    }
    // user graph
    mgemm<false, false, false, false><<<dim3(6, 79), blk, 0, stream>>>(
        user_embb, nullptr, FIN,
        Wcombb + (size_t)NUM_G * NC * FIN, FIN, xa, NC, nullptr, U_NODES, NC, FIN);
    aggregate_kernel<<<256, blk, 0, stream>>>(
        anchors, remapC + NUM_G * N_NODES, cnt + NUM_G * B_SZ, offs + NUM_G * B_SZ,
        elist, xa, u_bias, FRb + 256, 512);          // u_x -> FR[:, 256:]

    // --- head ---
    avg_kernel<<<B_SZ, blk, 0, stream>>>(outsb, X1b);
    mgemm<false, true, false, false><<<dim3(2, 8), blk, 0, stream>>>(
        X1b, nullptr, 512, a_rw_Wb, 512, X2b + 256, 512, a_rw_b, B_SZ, HCC, 512);
    mgemm<false, true, false, false><<<dim3(2, 8), blk, 0, stream>>>(
        X2b, nullptr, 512, pp_stp_Wb, 512, FRb, 512, pp_stp_b, B_SZ, HCC, 512);
    if (ws_fast)
        mgemm<false, false, false, true><<<dim3(8, 391), blk, 0, stream>>>(
            FRb, nullptr, 512, final_Wb, 512, ob, ITEMS, final_b, B_SZ, ITEMS, 512);
    else
        mgemm<false, false, true, true><<<dim3(8, 391), blk, 0, stream>>>(
            FRb, nullptr, 512, final_W, ITEMS, ob, ITEMS, final_b, B_SZ, ITEMS, 512);
}